// Round 1
// baseline (258.335 us; speedup 1.0000x reference)
//
#include <hip/hip_runtime.h>
#include <hip/hip_bf16.h>
#include <cstddef>

#define NNODE 4096
#define INF   512
#define OUTF  256
#define HID   8
#define CAP   128   // max degree; Binomial(4096,0.01) max ~67, 128 is >>5 sigma safe

typedef __attribute__((ext_vector_type(8))) short short8;
typedef __attribute__((ext_vector_type(4))) float f32x4;

__device__ __forceinline__ unsigned short f2bf(float f){
  unsigned int u = __float_as_uint(f);
  u += 0x7fffu + ((u >> 16) & 1u);   // round-to-nearest-even
  return (unsigned short)(u >> 16);
}

// ---------------------------------------------------------------- CSR build
// one block per row: scan 4096 floats, compact nonzero col indices (adj is {0,1})
__global__ __launch_bounds__(256) void build_csr(const float* __restrict__ adj,
                                                 int* __restrict__ deg,
                                                 int* __restrict__ cols){
  int row = blockIdx.x, tid = threadIdx.x;
  __shared__ int cnt;
  if (tid == 0) cnt = 0;
  __syncthreads();
  const float* arow = adj + (size_t)row * NNODE;
  int* crow = cols + (size_t)row * CAP;
  int lane = tid & 63;
  for (int k = 0; k < 16; k++){
    int c = k * 256 + tid;
    bool nz = arow[c] != 0.0f;
    unsigned long long m = __ballot(nz);
    int prefix = __popcll(m & ((1ull << lane) - 1ull));
    int wcount = __popcll(m);
    int base = 0;
    if (lane == 0 && wcount) base = atomicAdd(&cnt, wcount);
    base = __shfl(base, 0, 64);
    if (nz){
      int idx = base + prefix;
      if (idx < CAP) crow[idx] = c;
    }
  }
  __syncthreads();
  if (tid == 0) deg[row] = cnt > CAP ? CAP : cnt;
}

// ---------------------------------------------------------------- GAT pieces
// h = x @ W1 (4096x512 @ 512x8), dst[i] = h[i,:] . a1[8:16]; one wave per row
__global__ __launch_bounds__(256) void gat_h(const float* __restrict__ x,
                                             const float* __restrict__ W1,
                                             const float* __restrict__ a1,
                                             float* __restrict__ h,
                                             float* __restrict__ dstv){
  int wave = threadIdx.x >> 6, lane = threadIdx.x & 63;
  int row = blockIdx.x * 4 + wave;
  const float* xr = x + (size_t)row * INF;
  float acc[HID];
  #pragma unroll
  for (int f = 0; f < HID; f++) acc[f] = 0.f;
  for (int k = lane; k < INF; k += 64){
    float xv = xr[k];
    const float* wp = W1 + (size_t)k * HID;
    #pragma unroll
    for (int f = 0; f < HID; f++) acc[f] += xv * wp[f];
  }
  #pragma unroll
  for (int f = 0; f < HID; f++)
    for (int o = 32; o >= 1; o >>= 1) acc[f] += __shfl_xor(acc[f], o, 64);
  if (lane == 0){
    float d = 0.f;
    #pragma unroll
    for (int f = 0; f < HID; f++){ h[(size_t)row*HID + f] = acc[f]; d += acc[f] * a1[HID + f]; }
    dstv[row] = d;
  }
}

// p = softmax(scale * v) over n=4096, single block of 1024 threads
__global__ __launch_bounds__(1024) void softmax_vec(const float* __restrict__ v,
                                                    const float* __restrict__ scale_ptr,
                                                    float* __restrict__ p, int n){
  __shared__ float red[16];
  __shared__ float bcast;
  int tid = threadIdx.x;
  float s = scale_ptr ? scale_ptr[0] : 1.0f;
  float mx = -INFINITY;
  for (int i = tid; i < n; i += 1024) mx = fmaxf(mx, s * v[i]);
  for (int o = 32; o >= 1; o >>= 1) mx = fmaxf(mx, __shfl_xor(mx, o, 64));
  if ((tid & 63) == 0) red[tid >> 6] = mx;
  __syncthreads();
  if (tid == 0){ float t = red[0]; for (int i = 1; i < 16; i++) t = fmaxf(t, red[i]); bcast = t; }
  __syncthreads();
  mx = bcast;
  float sum = 0.f;
  for (int i = tid; i < n; i += 1024) sum += expf(s * v[i] - mx);
  for (int o = 32; o >= 1; o >>= 1) sum += __shfl_xor(sum, o, 64);
  if ((tid & 63) == 0) red[tid >> 6] = sum;
  __syncthreads();
  if (tid == 0){ float t = 0.f; for (int i = 0; i < 16; i++) t += red[i]; bcast = t; }
  __syncthreads();
  float inv = 1.0f / bcast;
  for (int i = tid; i < n; i += 1024) p[i] = expf(s * v[i] - mx) * inv;
}

// h1 = elu(sum_{j in N(i)} p[j]*h[j,:]);  h2 = h1 . W2   (8 lanes per row)
__global__ __launch_bounds__(256) void gat_agg1(const float* __restrict__ h,
                                                const float* __restrict__ p,
                                                const int* __restrict__ deg,
                                                const int* __restrict__ cols,
                                                const float* __restrict__ W2,
                                                float* __restrict__ h2){
  int tid = threadIdx.x;
  int f = tid & 7, rg = tid >> 3;
  int row = blockIdx.x * 32 + rg;
  const int* cl = cols + (size_t)row * CAP;
  int d = deg[row];
  float acc = 0.f;
  for (int n = 0; n < d; n++){
    int j = cl[n];
    acc += p[j] * h[(size_t)j * HID + f];
  }
  float e = acc > 0.f ? acc : expm1f(acc);
  float t = e * W2[f];
  t += __shfl_xor(t, 1, 64);
  t += __shfl_xor(t, 2, 64);
  t += __shfl_xor(t, 4, 64);
  if (f == 0) h2[row] = t;
}

// node_scores = elu(sum_{j in N(i)} p2[j]*h2[j]); mask = score > 0.7
__global__ __launch_bounds__(256) void scores_mask(const float* __restrict__ h2,
                                                   const float* __restrict__ p2,
                                                   const int* __restrict__ deg,
                                                   const int* __restrict__ cols,
                                                   float* __restrict__ maskf){
  int i = blockIdx.x * 256 + threadIdx.x;
  const int* cl = cols + (size_t)i * CAP;
  int d = deg[i];
  float s = 0.f;
  for (int n = 0; n < d; n++){
    int j = cl[n];
    s += p2[j] * h2[j];
  }
  float e = s > 0.f ? s : expm1f(s);
  maskf[i] = (e > 0.7f) ? 1.0f : 0.0f;
}

// ---------------------------------------------------------------- conversions
__global__ void convert_x(const float* __restrict__ x, unsigned short* __restrict__ xb){
  int stride = gridDim.x * blockDim.x;
  for (int t = blockIdx.x * blockDim.x + threadIdx.x; t < NNODE * INF / 4; t += stride){
    float4 v = ((const float4*)x)[t];
    ushort4 o;
    o.x = f2bf(v.x); o.y = f2bf(v.y); o.z = f2bf(v.z); o.w = f2bf(v.w);
    ((ushort4*)xb)[t] = o;
  }
}

// wbT[c][k] = bf16( W'[k][c] );  W'[k][c<256]=Wsgc[k][c],  W'[k][c>=256]=Wsgc[1024+k][c-256]
__global__ void convert_w(const float* __restrict__ Wsgc, unsigned short* __restrict__ wbT){
  int idx = blockIdx.x * 256 + threadIdx.x;   // 1024 blocks -> 262144
  if (idx >= 512 * 512) return;
  int c = idx >> 9, k = idx & 511;
  float val = (c < 256) ? Wsgc[(size_t)k * OUTF + c]
                        : Wsgc[(size_t)(1024 + k) * OUTF + (c - 256)];
  wbT[idx] = f2bf(val);
}

// ---------------------------------------------------------------- bf16 MFMA GEMM
// G[4096][512] = xb[4096][512] @ W'[512][512]   (BT is W' transposed, n-major)
// block tile 128x64, 4 waves in 2x2, each wave 4x2 grid of 16x16x32 MFMAs, BK=64
__global__ __launch_bounds__(256) void gemm_xw(const unsigned short* __restrict__ A,
                                               const unsigned short* __restrict__ BT,
                                               float* __restrict__ G){
  __shared__ unsigned short As[128][72];  // +8 pad: frag loads ~2-way instead of 16-way
  __shared__ unsigned short Bs[64][72];
  int tid = threadIdx.x;
  int wave = tid >> 6, lane = tid & 63;
  int row0 = blockIdx.x * 128;
  int col0 = blockIdx.y * 64;
  int wr = wave >> 1, wc = wave & 1;
  f32x4 acc[4][2];
  #pragma unroll
  for (int i = 0; i < 4; i++)
    #pragma unroll
    for (int j = 0; j < 2; j++)
      #pragma unroll
      for (int e = 0; e < 4; e++) acc[i][j][e] = 0.f;

  int mrow = lane & 15;
  int kq = (lane >> 4) * 8;

  for (int k0 = 0; k0 < 512; k0 += 64){
    #pragma unroll
    for (int ps = 0; ps < 4; ps++){            // stage A: 128 rows x 64 k
      int idx = ps * 256 + tid;
      int r = idx >> 3;
      int ko = (idx & 7) * 8;
      int4 v = *(const int4*)(A + ((size_t)(row0 + r) * 512 + k0 + ko));
      *(int4*)(&As[r][ko]) = v;
    }
    #pragma unroll
    for (int ps = 0; ps < 2; ps++){            // stage B^T: 64 cols x 64 k
      int idx = ps * 256 + tid;
      int c = idx >> 3;
      int ko = (idx & 7) * 8;
      int4 v = *(const int4*)(BT + ((size_t)(col0 + c) * 512 + k0 + ko));
      *(int4*)(&Bs[c][ko]) = v;
    }
    __syncthreads();
    #pragma unroll
    for (int kk = 0; kk < 2; kk++){
      short8 a[4], b[2];
      #pragma unroll
      for (int i = 0; i < 4; i++)
        a[i] = *(const short8*)(&As[wr * 64 + i * 16 + mrow][kk * 32 + kq]);
      #pragma unroll
      for (int j = 0; j < 2; j++)
        b[j] = *(const short8*)(&Bs[wc * 32 + j * 16 + mrow][kk * 32 + kq]);
      #pragma unroll
      for (int i = 0; i < 4; i++)
        #pragma unroll
        for (int j = 0; j < 2; j++)
          acc[i][j] = __builtin_amdgcn_mfma_f32_16x16x32_bf16(a[i], b[j], acc[i][j], 0, 0, 0);
    }
    __syncthreads();
  }
  int crow = (lane >> 4) * 4;   // C/D: col = lane&15, row = (lane>>4)*4 + reg  [m89/m91]
  int ccol = lane & 15;
  #pragma unroll
  for (int i = 0; i < 4; i++)
    #pragma unroll
    for (int j = 0; j < 2; j++)
      #pragma unroll
      for (int e = 0; e < 4; e++){
        int r = row0 + wr * 64 + i * 16 + crow + e;
        int c = col0 + wc * 32 + j * 16 + ccol;
        G[(size_t)r * 512 + c] = acc[i][j][e];
      }
}

// ---------------------------------------------------------------- sparse hop
// out[row][c] = sum_{j in N(row)} in[j*instride + c], 256 cols, one block per row
__global__ __launch_bounds__(256) void hop_kernel(const float* __restrict__ in, int instride,
                                                  float* __restrict__ out,
                                                  const int* __restrict__ deg,
                                                  const int* __restrict__ cols){
  int row = blockIdx.x, tid = threadIdx.x;
  const int* cl = cols + (size_t)row * CAP;
  int d = deg[row];
  float acc = 0.f;
  int n = 0;
  for (; n + 4 <= d; n += 4){
    int j0 = cl[n], j1 = cl[n + 1], j2 = cl[n + 2], j3 = cl[n + 3];
    float v0 = in[(size_t)j0 * instride + tid];
    float v1 = in[(size_t)j1 * instride + tid];
    float v2 = in[(size_t)j2 * instride + tid];
    float v3 = in[(size_t)j3 * instride + tid];
    acc += v0 + v1 + v2 + v3;
  }
  for (; n < d; n++) acc += in[(size_t)cl[n] * instride + tid];
  out[(size_t)row * OUTF + tid] = acc;
}

// out[i][c] = (mask[i] ? S1 : T3)[i][c] + b[c]
__global__ __launch_bounds__(256) void epilogue_kernel(const float* __restrict__ S1,
                                                       const float* __restrict__ T3,
                                                       const float* __restrict__ maskf,
                                                       const float* __restrict__ b,
                                                       float* __restrict__ out){
  int i = blockIdx.x, c = threadIdx.x;
  float m = maskf[i];
  float v = (m != 0.0f) ? S1[(size_t)i * OUTF + c] : T3[(size_t)i * OUTF + c];
  out[(size_t)i * OUTF + c] = v + b[c];
}

extern "C" void kernel_launch(void* const* d_in, const int* in_sizes, int n_in,
                              void* d_out, int out_size, void* d_ws, size_t ws_size,
                              hipStream_t stream) {
  const float* x    = (const float*)d_in[0];
  const float* adj  = (const float*)d_in[1];
  const float* W1   = (const float*)d_in[2];
  const float* a1   = (const float*)d_in[3];
  const float* W2   = (const float*)d_in[4];
  const float* a2   = (const float*)d_in[5];
  const float* Wsgc = (const float*)d_in[6];
  const float* bsgc = (const float*)d_in[7];
  float* out = (float*)d_out;

  char* w = (char*)d_ws;
  size_t off = 0;
  auto carve = [&](size_t bytes) -> char* {
    char* p = w + off;
    off += (bytes + 255) & ~(size_t)255;
    return p;
  };
  int*   deg   = (int*)carve((size_t)NNODE * 4);
  int*   cols  = (int*)carve((size_t)NNODE * CAP * 4);
  float* h     = (float*)carve((size_t)NNODE * HID * 4);
  float* dstv  = (float*)carve((size_t)NNODE * 4);
  float* p1    = (float*)carve((size_t)NNODE * 4);
  float* h2    = (float*)carve((size_t)NNODE * 4);
  float* p2    = (float*)carve((size_t)NNODE * 4);
  float* maskf = (float*)carve((size_t)NNODE * 4);
  unsigned short* xb  = (unsigned short*)carve((size_t)NNODE * INF * 2);
  unsigned short* wbT = (unsigned short*)carve((size_t)512 * 512 * 2);
  float* G  = (float*)carve((size_t)NNODE * 512 * 4);
  float* S1 = (float*)carve((size_t)NNODE * OUTF * 4);
  float* T1 = (float*)carve((size_t)NNODE * OUTF * 4);
  float* T2 = (float*)carve((size_t)NNODE * OUTF * 4);
  float* T3 = (float*)carve((size_t)NNODE * OUTF * 4);

  // 1. sparse structure from dense adj (read 67 MB exactly once)
  build_csr<<<NNODE, 256, 0, stream>>>(adj, deg, cols);

  // 2. GAT head -> per-row mask  (softmax(e,axis=1) collapses to softmax(dst))
  gat_h<<<NNODE / 4, 256, 0, stream>>>(x, W1, a1, h, dstv);
  softmax_vec<<<1, 1024, 0, stream>>>(dstv, nullptr, p1, NNODE);
  gat_agg1<<<NNODE / 32, 256, 0, stream>>>(h, p1, deg, cols, W2, h2);
  softmax_vec<<<1, 1024, 0, stream>>>(h2, a2 + 1, p2, NNODE);
  scores_mask<<<NNODE / 256, 256, 0, stream>>>(h2, p2, deg, cols, maskf);

  // 3. G = x @ [Wa | Wc] in bf16 MFMA (reassociated: (adj^k x)@W == adj^k (x@W))
  convert_x<<<1024, 256, 0, stream>>>(x, xb);
  convert_w<<<1024, 256, 0, stream>>>(Wsgc, wbT);
  dim3 gg(32, 8);
  gemm_xw<<<gg, 256, 0, stream>>>(xb, wbT, G);

  // 4. hops: 1 on left half (m=1 branch), 3 on right half (m=0 branch);
  //    middle SGC block is identically zero since mask*(1-mask)==0
  hop_kernel<<<NNODE, 256, 0, stream>>>(G, 512, S1, deg, cols);
  hop_kernel<<<NNODE, 256, 0, stream>>>(G + 256, 512, T1, deg, cols);
  hop_kernel<<<NNODE, 256, 0, stream>>>(T1, 256, T2, deg, cols);
  hop_kernel<<<NNODE, 256, 0, stream>>>(T2, 256, T3, deg, cols);

  // 5. per-row select + bias
  epilogue_kernel<<<NNODE, 256, 0, stream>>>(S1, T3, maskf, bsgc, out);
}

// Round 2
// 201.734 us; speedup vs baseline: 1.2806x; 1.2806x over previous
//
#include <hip/hip_runtime.h>
#include <hip/hip_bf16.h>
#include <cstddef>

#define NNODE 4096
#define INF   512
#define OUTF  256
#define HID   8
#define CAP   128   // max degree; Binomial(4096,0.01) max ~67, 128 is >>5 sigma safe

typedef __attribute__((ext_vector_type(8))) short short8;
typedef __attribute__((ext_vector_type(4))) float f32x4;

__device__ __forceinline__ unsigned short f2bf(float f){
  unsigned int u = __float_as_uint(f);
  u += 0x7fffu + ((u >> 16) & 1u);   // round-to-nearest-even
  return (unsigned short)(u >> 16);
}

// ---------------------------------------------------------------- CSR build
// one block per row: float4 scan of 4096 floats, per-thread atomic compaction.
// Neighbor ORDER is irrelevant (all consumers are sums), so no ballot needed.
__global__ __launch_bounds__(256) void build_csr(const float* __restrict__ adj,
                                                 int* __restrict__ deg,
                                                 int* __restrict__ cols){
  int row = blockIdx.x, tid = threadIdx.x;
  __shared__ int cnt;
  if (tid == 0) cnt = 0;
  __syncthreads();
  const float4* arow = (const float4*)(adj + (size_t)row * NNODE);
  int* crow = cols + (size_t)row * CAP;
  #pragma unroll
  for (int k = 0; k < 4; k++){
    int idx = k * 256 + tid;          // float4 index
    float4 v = arow[idx];
    int n0 = (v.x != 0.f), n1 = (v.y != 0.f), n2 = (v.z != 0.f), n3 = (v.w != 0.f);
    int m = n0 + n1 + n2 + n3;
    if (m){
      int base = atomicAdd(&cnt, m);
      int c = idx * 4;
      if (n0){ if (base < CAP) crow[base] = c;     base++; }
      if (n1){ if (base < CAP) crow[base] = c + 1; base++; }
      if (n2){ if (base < CAP) crow[base] = c + 2; base++; }
      if (n3){ if (base < CAP) crow[base] = c + 3; }
    }
  }
  __syncthreads();
  if (tid == 0) deg[row] = cnt > CAP ? CAP : cnt;
}

// ---------------------------------------------------------------- GAT pieces
// h = x @ W1 (4096x512 @ 512x8), dst[i] = h[i,:] . a1[8:16]; one wave per row
__global__ __launch_bounds__(256) void gat_h(const float* __restrict__ x,
                                             const float* __restrict__ W1,
                                             const float* __restrict__ a1,
                                             float* __restrict__ h,
                                             float* __restrict__ dstv){
  int wave = threadIdx.x >> 6, lane = threadIdx.x & 63;
  int row = blockIdx.x * 4 + wave;
  const float* xr = x + (size_t)row * INF;
  float acc[HID];
  #pragma unroll
  for (int f = 0; f < HID; f++) acc[f] = 0.f;
  for (int k = lane; k < INF; k += 64){
    float xv = xr[k];
    const float* wp = W1 + (size_t)k * HID;
    #pragma unroll
    for (int f = 0; f < HID; f++) acc[f] += xv * wp[f];
  }
  #pragma unroll
  for (int f = 0; f < HID; f++)
    for (int o = 32; o >= 1; o >>= 1) acc[f] += __shfl_xor(acc[f], o, 64);
  if (lane == 0){
    float d = 0.f;
    #pragma unroll
    for (int f = 0; f < HID; f++){ h[(size_t)row*HID + f] = acc[f]; d += acc[f] * a1[HID + f]; }
    dstv[row] = d;
  }
}

// layer-1 aggregate with INLINE softmax: block prologue computes
// p = softmax(dstv) into LDS (redundant per block, 16 KB L2-resident source),
// then h1=elu(sum p[j] h[j,:]), h2 = h1.W2.  8 lanes per row, 32 rows/block.
__global__ __launch_bounds__(256) void gat_agg1_f(const float* __restrict__ h,
                                                  const float* __restrict__ dstv,
                                                  const int* __restrict__ deg,
                                                  const int* __restrict__ cols,
                                                  const float* __restrict__ W2,
                                                  float* __restrict__ h2){
  __shared__ float p[NNODE];
  __shared__ float red[4];
  int tid = threadIdx.x, lane = tid & 63, wv = tid >> 6;
  float mx = -INFINITY;
  for (int i = tid; i < NNODE; i += 256) mx = fmaxf(mx, dstv[i]);
  #pragma unroll
  for (int o = 32; o >= 1; o >>= 1) mx = fmaxf(mx, __shfl_xor(mx, o, 64));
  if (lane == 0) red[wv] = mx;
  __syncthreads();
  mx = fmaxf(fmaxf(red[0], red[1]), fmaxf(red[2], red[3]));
  __syncthreads();
  float sum = 0.f;
  for (int i = tid; i < NNODE; i += 256){ float e = expf(dstv[i] - mx); p[i] = e; sum += e; }
  #pragma unroll
  for (int o = 32; o >= 1; o >>= 1) sum += __shfl_xor(sum, o, 64);
  if (lane == 0) red[wv] = sum;
  __syncthreads();
  float inv = 1.0f / (red[0] + red[1] + red[2] + red[3]);
  for (int i = tid; i < NNODE; i += 256) p[i] *= inv;
  __syncthreads();

  int f = tid & 7, rg = tid >> 3;
  int row = blockIdx.x * 32 + rg;
  const int* cl = cols + (size_t)row * CAP;
  int d = deg[row];
  float acc = 0.f;
  for (int n = 0; n < d; n++){
    int j = cl[n];
    acc += p[j] * h[(size_t)j * HID + f];
  }
  float e = acc > 0.f ? acc : expm1f(acc);
  float t = e * W2[f];
  t += __shfl_xor(t, 1, 64);
  t += __shfl_xor(t, 2, 64);
  t += __shfl_xor(t, 4, 64);
  if (f == 0) h2[row] = t;
}

// layer-2 scores with INLINE softmax: q[j] = softmax(a2[1]*h2)[j]*h2[j] in LDS,
// node_score[i] = elu(sum_{j in N(i)} q[j]); mask = score > 0.7
__global__ __launch_bounds__(256) void scores_mask_f(const float* __restrict__ h2,
                                                     const float* __restrict__ a2,
                                                     const int* __restrict__ deg,
                                                     const int* __restrict__ cols,
                                                     float* __restrict__ maskf){
  __shared__ float q[NNODE];
  __shared__ float red[4];
  int tid = threadIdx.x, lane = tid & 63, wv = tid >> 6;
  float s2 = a2[1];
  float mx = -INFINITY;
  for (int i = tid; i < NNODE; i += 256) mx = fmaxf(mx, s2 * h2[i]);
  #pragma unroll
  for (int o = 32; o >= 1; o >>= 1) mx = fmaxf(mx, __shfl_xor(mx, o, 64));
  if (lane == 0) red[wv] = mx;
  __syncthreads();
  mx = fmaxf(fmaxf(red[0], red[1]), fmaxf(red[2], red[3]));
  __syncthreads();
  float sum = 0.f;
  for (int i = tid; i < NNODE; i += 256){ float e = expf(s2 * h2[i] - mx); q[i] = e; sum += e; }
  #pragma unroll
  for (int o = 32; o >= 1; o >>= 1) sum += __shfl_xor(sum, o, 64);
  if (lane == 0) red[wv] = sum;
  __syncthreads();
  float inv = 1.0f / (red[0] + red[1] + red[2] + red[3]);
  for (int i = tid; i < NNODE; i += 256) q[i] = q[i] * inv * h2[i];
  __syncthreads();

  int row = blockIdx.x * 256 + tid;
  const int* cl = cols + (size_t)row * CAP;
  int d = deg[row];
  float s = 0.f;
  for (int n = 0; n < d; n++) s += q[cl[n]];
  float e = s > 0.f ? s : expm1f(s);
  maskf[row] = (e > 0.7f) ? 1.0f : 0.0f;
}

// ---------------------------------------------------------------- W' convert
// wbT[c][k] = bf16( W'[k][c] );  W'[k][c<256]=Wsgc[k][c],  W'[k][c>=256]=Wsgc[1024+k][c-256]
__global__ void convert_w(const float* __restrict__ Wsgc, unsigned short* __restrict__ wbT){
  int idx = blockIdx.x * 256 + threadIdx.x;   // 1024 blocks -> 262144
  if (idx >= 512 * 512) return;
  int c = idx >> 9, k = idx & 511;
  float val = (c < 256) ? Wsgc[(size_t)k * OUTF + c]
                        : Wsgc[(size_t)(1024 + k) * OUTF + (c - 256)];
  wbT[idx] = f2bf(val);
}

// ---------------------------------------------------------------- bf16 MFMA GEMM
// G[4096][512] = bf16(x)[4096][512] @ W'[512][512]; A converted fp32->bf16 in-flight.
// block tile 128x64, 4 waves in 2x2, each wave 4x2 grid of 16x16x32 MFMAs, BK=64
__global__ __launch_bounds__(256) void gemm_xw(const float* __restrict__ X,
                                               const unsigned short* __restrict__ BT,
                                               float* __restrict__ G){
  __shared__ unsigned short As[128][72];  // +8 pad
  __shared__ unsigned short Bs[64][72];
  int tid = threadIdx.x;
  int wave = tid >> 6, lane = tid & 63;
  int row0 = blockIdx.x * 128;
  int col0 = blockIdx.y * 64;
  int wr = wave >> 1, wc = wave & 1;
  f32x4 acc[4][2];
  #pragma unroll
  for (int i = 0; i < 4; i++)
    #pragma unroll
    for (int j = 0; j < 2; j++)
      #pragma unroll
      for (int e = 0; e < 4; e++) acc[i][j][e] = 0.f;

  int mrow = lane & 15;
  int kq = (lane >> 4) * 8;

  for (int k0 = 0; k0 < 512; k0 += 64){
    #pragma unroll
    for (int ps = 0; ps < 4; ps++){            // stage A: fp32 load -> bf16 LDS
      int idx = ps * 256 + tid;
      int r = idx >> 3;
      int ko = (idx & 7) * 8;
      const float* src = X + ((size_t)(row0 + r) * 512 + k0 + ko);
      float4 v0 = ((const float4*)src)[0];
      float4 v1 = ((const float4*)src)[1];
      union { short8 v; unsigned short u[8]; } pk;
      pk.u[0] = f2bf(v0.x); pk.u[1] = f2bf(v0.y); pk.u[2] = f2bf(v0.z); pk.u[3] = f2bf(v0.w);
      pk.u[4] = f2bf(v1.x); pk.u[5] = f2bf(v1.y); pk.u[6] = f2bf(v1.z); pk.u[7] = f2bf(v1.w);
      *(short8*)(&As[r][ko]) = pk.v;
    }
    #pragma unroll
    for (int ps = 0; ps < 2; ps++){            // stage B^T: 64 cols x 64 k (bf16)
      int idx = ps * 256 + tid;
      int c = idx >> 3;
      int ko = (idx & 7) * 8;
      int4 v = *(const int4*)(BT + ((size_t)(col0 + c) * 512 + k0 + ko));
      *(int4*)(&Bs[c][ko]) = v;
    }
    __syncthreads();
    #pragma unroll
    for (int kk = 0; kk < 2; kk++){
      short8 a[4], b[2];
      #pragma unroll
      for (int i = 0; i < 4; i++)
        a[i] = *(const short8*)(&As[wr * 64 + i * 16 + mrow][kk * 32 + kq]);
      #pragma unroll
      for (int j = 0; j < 2; j++)
        b[j] = *(const short8*)(&Bs[wc * 32 + j * 16 + mrow][kk * 32 + kq]);
      #pragma unroll
      for (int i = 0; i < 4; i++)
        #pragma unroll
        for (int j = 0; j < 2; j++)
          acc[i][j] = __builtin_amdgcn_mfma_f32_16x16x32_bf16(a[i], b[j], acc[i][j], 0, 0, 0);
    }
    __syncthreads();
  }
  int crow = (lane >> 4) * 4;   // C/D: col = lane&15, row = (lane>>4)*4 + reg  [m89/m91]
  int ccol = lane & 15;
  #pragma unroll
  for (int i = 0; i < 4; i++)
    #pragma unroll
    for (int j = 0; j < 2; j++)
      #pragma unroll
      for (int e = 0; e < 4; e++){
        int r = row0 + wr * 64 + i * 16 + crow + e;
        int c = col0 + wc * 32 + j * 16 + ccol;
        G[(size_t)r * 512 + c] = acc[i][j][e];
      }
}

// ---------------------------------------------------------------- sparse hops
// wave-per-row, float4-per-lane: out[row][:] = sum_{j in N(row)} in[j][:256]
__global__ __launch_bounds__(256) void hop4(const float* __restrict__ in, int instride,
                                            float* __restrict__ out,
                                            const int* __restrict__ deg,
                                            const int* __restrict__ cols){
  int wave = threadIdx.x >> 6, lane = threadIdx.x & 63;
  int row = blockIdx.x * 4 + wave;
  const int* cl = cols + (size_t)row * CAP;
  int d = deg[row];
  f32x4 acc = {0.f, 0.f, 0.f, 0.f};
  int n = 0;
  for (; n + 4 <= d; n += 4){
    int j0 = cl[n], j1 = cl[n+1], j2 = cl[n+2], j3 = cl[n+3];
    f32x4 a = ((const f32x4*)(in + (size_t)j0 * instride))[lane];
    f32x4 b = ((const f32x4*)(in + (size_t)j1 * instride))[lane];
    f32x4 c = ((const f32x4*)(in + (size_t)j2 * instride))[lane];
    f32x4 e = ((const f32x4*)(in + (size_t)j3 * instride))[lane];
    acc += a + b + c + e;
  }
  for (; n < d; n++)
    acc += ((const f32x4*)(in + (size_t)cl[n] * instride))[lane];
  ((f32x4*)(out + (size_t)row * OUTF))[lane] = acc;
}

// final hop + epilogue fused with per-row pruning:
// mask=1 rows need only adj@G_left; mask=0 rows need only adj@T2.  + bias.
__global__ __launch_bounds__(256) void hop_final(const float* __restrict__ Gleft,
                                                 const float* __restrict__ T2,
                                                 const float* __restrict__ maskf,
                                                 const float* __restrict__ b,
                                                 float* __restrict__ out,
                                                 const int* __restrict__ deg,
                                                 const int* __restrict__ cols){
  int wave = threadIdx.x >> 6, lane = threadIdx.x & 63;
  int row = blockIdx.x * 4 + wave;
  const int* cl = cols + (size_t)row * CAP;
  int d = deg[row];
  bool m = maskf[row] != 0.0f;             // wave-uniform
  const float* in = m ? Gleft : T2;
  int instride    = m ? 512   : 256;
  f32x4 acc = {0.f, 0.f, 0.f, 0.f};
  int n = 0;
  for (; n + 4 <= d; n += 4){
    int j0 = cl[n], j1 = cl[n+1], j2 = cl[n+2], j3 = cl[n+3];
    f32x4 a = ((const f32x4*)(in + (size_t)j0 * instride))[lane];
    f32x4 bb = ((const f32x4*)(in + (size_t)j1 * instride))[lane];
    f32x4 c = ((const f32x4*)(in + (size_t)j2 * instride))[lane];
    f32x4 e = ((const f32x4*)(in + (size_t)j3 * instride))[lane];
    acc += a + bb + c + e;
  }
  for (; n < d; n++)
    acc += ((const f32x4*)(in + (size_t)cl[n] * instride))[lane];
  f32x4 bias = ((const f32x4*)b)[lane];
  ((f32x4*)(out + (size_t)row * OUTF))[lane] = acc + bias;
}

extern "C" void kernel_launch(void* const* d_in, const int* in_sizes, int n_in,
                              void* d_out, int out_size, void* d_ws, size_t ws_size,
                              hipStream_t stream) {
  const float* x    = (const float*)d_in[0];
  const float* adj  = (const float*)d_in[1];
  const float* W1   = (const float*)d_in[2];
  const float* a1   = (const float*)d_in[3];
  const float* W2   = (const float*)d_in[4];
  const float* a2   = (const float*)d_in[5];
  const float* Wsgc = (const float*)d_in[6];
  const float* bsgc = (const float*)d_in[7];
  float* out = (float*)d_out;

  char* w = (char*)d_ws;
  size_t off = 0;
  auto carve = [&](size_t bytes) -> char* {
    char* p = w + off;
    off += (bytes + 255) & ~(size_t)255;
    return p;
  };
  int*   deg   = (int*)carve((size_t)NNODE * 4);
  int*   cols  = (int*)carve((size_t)NNODE * CAP * 4);
  float* h     = (float*)carve((size_t)NNODE * HID * 4);
  float* dstv  = (float*)carve((size_t)NNODE * 4);
  float* h2    = (float*)carve((size_t)NNODE * 4);
  float* maskf = (float*)carve((size_t)NNODE * 4);
  unsigned short* wbT = (unsigned short*)carve((size_t)512 * 512 * 2);
  float* G  = (float*)carve((size_t)NNODE * 512 * 4);
  float* T1 = (float*)carve((size_t)NNODE * OUTF * 4);
  float* T2 = (float*)carve((size_t)NNODE * OUTF * 4);

  // 1. sparse structure from dense adj (67 MB read once — HBM floor ~11 us)
  build_csr<<<NNODE, 256, 0, stream>>>(adj, deg, cols);

  // 2. GAT head -> mask (softmax(e,axis=1) collapses to softmax(dst); inlined)
  gat_h<<<NNODE / 4, 256, 0, stream>>>(x, W1, a1, h, dstv);
  gat_agg1_f<<<NNODE / 32, 256, 0, stream>>>(h, dstv, deg, cols, W2, h2);
  scores_mask_f<<<NNODE / 256, 256, 0, stream>>>(h2, a2, deg, cols, maskf);

  // 3. G = x @ [Wa | Wc] bf16 MFMA ((adj^k x)@W == adj^k (x@W)); A cast in-flight
  convert_w<<<1024, 256, 0, stream>>>(Wsgc, wbT);
  dim3 gg(32, 8);
  gemm_xw<<<gg, 256, 0, stream>>>(x, wbT, G);

  // 4. hops; middle SGC block is identically zero (mask*(1-mask)==0);
  //    final hop pruned per row by mask and fused with select+bias epilogue
  hop4<<<NNODE / 4, 256, 0, stream>>>(G + 256, 512, T1, deg, cols);
  hop4<<<NNODE / 4, 256, 0, stream>>>(T1, 256, T2, deg, cols);
  hop_final<<<NNODE / 4, 256, 0, stream>>>(G, T2, maskf, bsgc, out, deg, cols);
}